// Round 3
// baseline (457.030 us; speedup 1.0000x reference)
//
#include <hip/hip_runtime.h>
#include <math.h>

#define B_    16
#define M_    8
#define T_    250
#define L_    1024
#define NPAIR 28

#define KTOT   1024
#define CH_K   256
#define APITCH 264      // 256 + 8 halfs pad; row stride 528 B (16B multiple)
#define NKT    8
#define NCHUNK 4
#define ZPITCH 1056     // SWZ(1023)+1 rounded

typedef _Float16 half8  __attribute__((ext_vector_type(8)));
typedef _Float16 half2t __attribute__((ext_vector_type(2)));
typedef float    floatx4 __attribute__((ext_vector_type(4)));

__device__ __align__(16) _Float16 g_Btw[64 * KTOT];

// np.triu_indices(8, k=1)
__constant__ int c_i1[NPAIR] = {0,0,0,0,0,0,0,1,1,1,1,1,1,2,2,2,2,2,3,3,3,3,4,4,4,5,5,6};
__constant__ int c_i2[NPAIR] = {1,2,3,4,5,6,7,2,3,4,5,6,7,3,4,5,6,7,4,5,6,7,5,6,7,6,7,7};

// B[n][k]: k=0 -> DC (1/1024); k=1 -> Nyquist slot ((-1)^n/1024); k=2b -> 2cos/1024, 2b+1 -> -2sin/1024
__global__ void init_btw() {
    int idx = blockIdx.x * 256 + threadIdx.x;
    int n = idx >> 10, k = idx & 1023;
    float v;
    if (k == 0)      v = 1.0f / 1024.0f;
    else if (k == 1) v = (n & 1) ? (-1.0f / 1024.0f) : (1.0f / 1024.0f);
    else {
        int bin = k >> 1, tau = n - 32;
        int r = (tau * bin) & 1023;
        float ang = (float)r * (6.283185307179586f / 1024.0f);
        float s, c; sincosf(ang, &s, &c);
        v = ((k & 1) ? -s : c) * (2.0f / 1024.0f);
    }
    g_Btw[idx] = (_Float16)v;
}

#define SWZ(i) ((i) + ((i) >> 5))

__device__ inline float2 cmul(float2 a, float2 b) {
    return make_float2(fmaf(a.x, b.x, -a.y * b.y), fmaf(a.x, b.y, a.y * b.x));
}
__device__ inline float2 cadd(float2 a, float2 b) { return make_float2(a.x + b.x, a.y + b.y); }
__device__ inline float2 csub(float2 a, float2 b) { return make_float2(a.x - b.x, a.y - b.y); }
__device__ inline float2 cmni(float2 a) { return make_float2(a.y, -a.x); }  // a * (-i)

// DIF 8-point DFT: y_k = sum_r v_r W8^{rk}, in place
__device__ inline void dft8(float2 v[8]) {
    const float rt = 0.70710678118654752440f;
    float2 b0 = cadd(v[0], v[4]), b1 = cadd(v[1], v[5]);
    float2 b2 = cadd(v[2], v[6]), b3 = cadd(v[3], v[7]);
    float2 c0 = csub(v[0], v[4]);
    float2 t1 = csub(v[1], v[5]);
    float2 c1 = make_float2(rt * (t1.x + t1.y), rt * (t1.y - t1.x));   // *W8^1
    float2 c2 = cmni(csub(v[2], v[6]));                                 // *W8^2
    float2 t3 = csub(v[3], v[7]);
    float2 c3 = make_float2(rt * (t3.y - t3.x), -rt * (t3.x + t3.y));  // *W8^3
    float2 f0 = cadd(b0, b2), f1 = cadd(b1, b3);
    float2 g0 = csub(b0, b2), g1 = cmni(csub(b1, b3));
    v[0] = cadd(f0, f1); v[4] = csub(f0, f1);
    v[2] = cadd(g0, g1); v[6] = csub(g0, g1);
    f0 = cadd(c0, c2); f1 = cadd(c1, c3);
    g0 = csub(c0, c2); g1 = cmni(csub(c1, c3));
    v[1] = cadd(f0, f1); v[5] = csub(f0, f1);
    v[3] = cadd(g0, g1); v[7] = csub(g0, g1);
}

__device__ inline void twiddle8(float2 v[8], float2 w1) {
    float2 w = w1;
    v[1] = cmul(v[1], w);
#pragma unroll
    for (int k = 2; k < 8; ++k) { w = cmul(w, w1); v[k] = cmul(v[k], w); }
}

// DIF radices (2,8,8,8): X[k] sits at p(k)
__device__ inline int posmap(int k) {
    return ((k & 1) << 9) | (((k >> 1) & 7) << 6) | (((k >> 4) & 7) << 3) | ((k >> 7) & 7);
}

__global__ __launch_bounds__(512, 6) void gcc_main(const float* __restrict__ x,
                                                   float* __restrict__ out) {
    __shared__ float2 s_z[4 * ZPITCH];                                  // 33792 B
    __shared__ __align__(16) union { float2 lut[512]; _Float16 A[32 * APITCH]; } su; // 16896 B

    const int tid = threadIdx.x;
    const int t = blockIdx.x, b = blockIdx.y;
    const int f = tid & 127, c = tid >> 7;
    float2* Zb = s_z + c * ZPITCH;

    // lut[m] = W_1024^m = e^{-2 pi i m / 1024}, m in [0,512)
    {
        float s, cv, ang = (float)tid * (-6.283185307179586f / 1024.0f);
        sincosf(ang, &s, &cv);
        su.lut[tid] = make_float2(cv, s);
    }

    // ---- load: pack channels (2c, 2c+1) into complex Z_c ----
    const float* xa = x + (((size_t)b * M_ + 2 * c) * T_ + t) * L_;
    const float* xb = xa + (size_t)T_ * L_;
#pragma unroll
    for (int e = 0; e < 2; ++e) {
        float4 va = *(const float4*)(xa + f * 8 + e * 4);
        float4 vb = *(const float4*)(xb + f * 8 + e * 4);
        int i = f * 8 + e * 4;
        Zb[SWZ(i + 0)] = make_float2(va.x, vb.x);
        Zb[SWZ(i + 1)] = make_float2(va.y, vb.y);
        Zb[SWZ(i + 2)] = make_float2(va.z, vb.z);
        Zb[SWZ(i + 3)] = make_float2(va.w, vb.w);
    }
    __syncthreads();

    // ---- Stage A: radix-2, stride 512, twiddle W_1024^u ----
#pragma unroll
    for (int q = 0; q < 4; ++q) {
        int u = f + 128 * q;
        float2 a = Zb[SWZ(u)], d = Zb[SWZ(u + 512)];
        Zb[SWZ(u)]       = cadd(a, d);
        Zb[SWZ(u + 512)] = cmul(csub(a, d), su.lut[u]);
    }
    __syncthreads();

    // ---- Stage B: radix-8 on two length-512 subs, stride 64 ----
    {
        const int base = (f >> 6) * 512 + (f & 63);
        float2 v[8];
#pragma unroll
        for (int r = 0; r < 8; ++r) v[r] = Zb[SWZ(base + 64 * r)];
        dft8(v);
        twiddle8(v, su.lut[2 * (f & 63)]);
#pragma unroll
        for (int k = 0; k < 8; ++k) Zb[SWZ(base + 64 * k)] = v[k];
    }
    __syncthreads();

    // ---- Stage C: radix-8 on 16 length-64 subs, stride 8 ----
    {
        const int base = (f >> 3) * 64 + (f & 7);
        float2 v[8];
#pragma unroll
        for (int r = 0; r < 8; ++r) v[r] = Zb[SWZ(base + 8 * r)];
        dft8(v);
        twiddle8(v, su.lut[16 * (f & 7)]);
#pragma unroll
        for (int k = 0; k < 8; ++k) Zb[SWZ(base + 8 * k)] = v[k];
    }
    __syncthreads();

    // ---- Stage D: radix-8 on 128 length-8 subs, stride 1 (no twiddle) ----
    {
        const int base = f * 8;
        float2 v[8];
#pragma unroll
        for (int r = 0; r < 8; ++r) v[r] = Zb[SWZ(base + r)];
        dft8(v);
#pragma unroll
        for (int k = 0; k < 8; ++k) Zb[SWZ(base + k)] = v[k];
    }
    __syncthreads();

    // ---- Phases 2+3 ----
    const int lane = tid & 63, wv = tid >> 6;
    const int mt = wv >> 2, nt = wv & 3;
    const int l15 = lane & 15, quad = lane >> 4;
    const int arow = mt * 16 + l15;
    const _Float16* Bbase = g_Btw + (nt * 16 + l15) * KTOT;
    floatx4 acc = {0.0f, 0.0f, 0.0f, 0.0f};

    const int bl = tid & 127, pg = tid >> 7;   // A-fill: (bin-local, pair-group of 7)

    for (int h = 0; h < NCHUNK; ++h) {
        {
            const int beta = h * 128 + bl;
            const int pa = posmap(beta);
            const int pb = posmap((1024 - beta) & 1023);
            float2 Xs[8];
#pragma unroll
            for (int cc = 0; cc < 4; ++cc) {
                float2 Aa = s_z[cc * ZPITCH + SWZ(pa)];
                float2 Bb = s_z[cc * ZPITCH + SWZ(pb)];
                Xs[2 * cc]     = make_float2(0.5f * (Aa.x + Bb.x), 0.5f * (Aa.y - Bb.y));
                Xs[2 * cc + 1] = make_float2(0.5f * (Aa.y + Bb.y), 0.5f * (Bb.x - Aa.x));
            }
#pragma unroll
            for (int pp = 0; pp < 7; ++pp) {
                const int p = pg * 7 + pp;
                float2 X1 = Xs[c_i1[p]], X2 = Xs[c_i2[p]];
                float rr = X1.x * X2.x + X1.y * X2.y;
                float ri = X1.y * X2.x - X1.x * X2.y;
                float m2 = rr * rr + ri * ri;
                float inv = (m2 > 1e-30f) ? rsqrtf(m2) : 0.0f;
                *(half2t*)&su.A[p * APITCH + 2 * bl] =
                    (half2t){(_Float16)(rr * inv), (_Float16)(ri * inv)};
            }
            if (h == 0 && bl == 0) {           // Nyquist -> hijacked col k=1
#pragma unroll
                for (int pp = 0; pp < 7; ++pp) {
                    const int p = pg * 7 + pp;
                    const int pN = posmap(512); // = 4
                    float x1, x2, c1 = c_i1[p], c2 = c_i2[p];
                    float2 Za = s_z[(c_i1[p] >> 1) * ZPITCH + SWZ(pN)];
                    float2 Zc = s_z[(c_i2[p] >> 1) * ZPITCH + SWZ(pN)];
                    x1 = (c_i1[p] & 1) ? Za.y : Za.x;
                    x2 = (c_i2[p] & 1) ? Zc.y : Zc.x;
                    float rr = x1 * x2;
                    float inv = (rr * rr > 1e-30f) ? rsqrtf(rr * rr) : 0.0f;
                    su.A[p * APITCH + 1] = (_Float16)(rr * inv);
                    (void)c1; (void)c2;
                }
            }
        }
        __syncthreads();

        const _Float16* Ap = su.A + arow * APITCH;
        const _Float16* Bp = Bbase + h * CH_K;
#pragma unroll
        for (int kt = 0; kt < NKT; ++kt) {
            half8 af = *(const half8*)(Ap + kt * 32 + quad * 8);
            half8 bf = *(const half8*)(Bp + kt * 32 + quad * 8);
            acc = __builtin_amdgcn_mfma_f32_16x16x32_f16(af, bf, acc, 0, 0, 0);
        }
        __syncthreads();
    }

    // ---- Epilogue: C/D layout col=lane&15, row=quad*4+reg ----
#pragma unroll
    for (int r = 0; r < 4; ++r) {
        int pair = mt * 16 + quad * 4 + r;
        if (pair < NPAIR)
            out[((((size_t)b * NPAIR + pair) * T_ + t) << 6) + nt * 16 + l15] = acc[r];
    }
}

extern "C" void kernel_launch(void* const* d_in, const int* in_sizes, int n_in,
                              void* d_out, int out_size, void* d_ws, size_t ws_size,
                              hipStream_t stream) {
    (void)in_sizes; (void)n_in; (void)d_ws; (void)ws_size; (void)out_size;
    hipLaunchKernelGGL(init_btw, dim3(256), dim3(256), 0, stream);
    hipLaunchKernelGGL(gcc_main, dim3(T_, B_), dim3(512), 0, stream,
                       (const float*)d_in[0], (float*)d_out);
}

// Round 4
// 416.808 us; speedup vs baseline: 1.0965x; 1.0965x over previous
//
#include <hip/hip_runtime.h>
#include <math.h>

#define B_    16
#define M_    8
#define T_    250
#define L_    1024
#define NPAIR 28

#define KTOT   1024
#define CH_K   256
#define APITCH 264      // 256 + 8 halfs pad; row stride 528 B (16B multiple)
#define NKT    8
#define NCHUNK 4
#define ZPITCH 1056     // SWZ(1023)+1 rounded

typedef _Float16 half8  __attribute__((ext_vector_type(8)));
typedef _Float16 half2t __attribute__((ext_vector_type(2)));
typedef float    floatx4 __attribute__((ext_vector_type(4)));

__device__ __align__(16) _Float16 g_Btw[64 * KTOT];

// np.triu_indices(8, k=1)
__constant__ int c_i1[NPAIR] = {0,0,0,0,0,0,0,1,1,1,1,1,1,2,2,2,2,2,3,3,3,3,4,4,4,5,5,6};
__constant__ int c_i2[NPAIR] = {1,2,3,4,5,6,7,2,3,4,5,6,7,3,4,5,6,7,4,5,6,7,5,6,7,6,7,7};

// B[n][k]: k=0 -> DC (1/1024); k=1 -> Nyquist slot ((-1)^n/1024); k=2b -> 2cos/1024, 2b+1 -> -2sin/1024
__global__ void init_btw() {
    int idx = blockIdx.x * 256 + threadIdx.x;
    int n = idx >> 10, k = idx & 1023;
    float v;
    if (k == 0)      v = 1.0f / 1024.0f;
    else if (k == 1) v = (n & 1) ? (-1.0f / 1024.0f) : (1.0f / 1024.0f);
    else {
        int bin = k >> 1, tau = n - 32;
        int r = (tau * bin) & 1023;
        float ang = (float)r * (6.283185307179586f / 1024.0f);
        float s, c; sincosf(ang, &s, &c);
        v = ((k & 1) ? -s : c) * (2.0f / 1024.0f);
    }
    g_Btw[idx] = (_Float16)v;
}

#define SWZ(i) ((i) + ((i) >> 5))

__device__ inline float2 cmul(float2 a, float2 b) {
    return make_float2(fmaf(a.x, b.x, -a.y * b.y), fmaf(a.x, b.y, a.y * b.x));
}
__device__ inline float2 cadd(float2 a, float2 b) { return make_float2(a.x + b.x, a.y + b.y); }
__device__ inline float2 csub(float2 a, float2 b) { return make_float2(a.x - b.x, a.y - b.y); }
__device__ inline float2 cmni(float2 a) { return make_float2(a.y, -a.x); }  // a * (-i)

// DIF 8-point DFT: y_k = sum_r v_r W8^{rk}, in place
__device__ inline void dft8(float2 v[8]) {
    const float rt = 0.70710678118654752440f;
    float2 b0 = cadd(v[0], v[4]), b1 = cadd(v[1], v[5]);
    float2 b2 = cadd(v[2], v[6]), b3 = cadd(v[3], v[7]);
    float2 c0 = csub(v[0], v[4]);
    float2 t1 = csub(v[1], v[5]);
    float2 c1 = make_float2(rt * (t1.x + t1.y), rt * (t1.y - t1.x));   // *W8^1
    float2 c2 = cmni(csub(v[2], v[6]));                                 // *W8^2
    float2 t3 = csub(v[3], v[7]);
    float2 c3 = make_float2(rt * (t3.y - t3.x), -rt * (t3.x + t3.y));  // *W8^3
    float2 f0 = cadd(b0, b2), f1 = cadd(b1, b3);
    float2 g0 = csub(b0, b2), g1 = cmni(csub(b1, b3));
    v[0] = cadd(f0, f1); v[4] = csub(f0, f1);
    v[2] = cadd(g0, g1); v[6] = csub(g0, g1);
    f0 = cadd(c0, c2); f1 = cadd(c1, c3);
    g0 = csub(c0, c2); g1 = cmni(csub(c1, c3));
    v[1] = cadd(f0, f1); v[5] = csub(f0, f1);
    v[3] = cadd(g0, g1); v[7] = csub(g0, g1);
}

__device__ inline void twiddle8(float2 v[8], float2 w1) {
    float2 w = w1;
    v[1] = cmul(v[1], w);
#pragma unroll
    for (int k = 2; k < 8; ++k) { w = cmul(w, w1); v[k] = cmul(v[k], w); }
}

// DIF radices (2,8,8,8): X[k] sits at p(k)
__device__ inline int posmap(int k) {
    return ((k & 1) << 9) | (((k >> 1) & 7) << 6) | (((k >> 4) & 7) << 3) | ((k >> 7) & 7);
}

__global__ __launch_bounds__(512, 4) void gcc_main(const float* __restrict__ x,
                                                   float* __restrict__ out) {
    __shared__ float2 s_z[4 * ZPITCH];                                  // 33792 B
    // lut (4 KB) overlaps A[0]; lut's last use (stage C) precedes first A[0] write
    __shared__ __align__(16) union {
        float2   lut[512];
        _Float16 A[2][32 * APITCH];
    } su;                                                               // 33792 B

    const int tid = threadIdx.x;
    const int t = blockIdx.x, b = blockIdx.y;
    const int f = tid & 127, c = tid >> 7;
    float2* Zb = s_z + c * ZPITCH;

    // lut[m] = W_1024^m = e^{-2 pi i m / 1024}, m in [0,512)
    {
        float s, cv, ang = (float)tid * (-6.283185307179586f / 1024.0f);
        sincosf(ang, &s, &cv);
        su.lut[tid] = make_float2(cv, s);
    }

    // ---- load: pack channels (2c, 2c+1) into complex Z_c ----
    const float* xa = x + (((size_t)b * M_ + 2 * c) * T_ + t) * L_;
    const float* xb = xa + (size_t)T_ * L_;
#pragma unroll
    for (int e = 0; e < 2; ++e) {
        float4 va = *(const float4*)(xa + f * 8 + e * 4);
        float4 vb = *(const float4*)(xb + f * 8 + e * 4);
        int i = f * 8 + e * 4;
        Zb[SWZ(i + 0)] = make_float2(va.x, vb.x);
        Zb[SWZ(i + 1)] = make_float2(va.y, vb.y);
        Zb[SWZ(i + 2)] = make_float2(va.z, vb.z);
        Zb[SWZ(i + 3)] = make_float2(va.w, vb.w);
    }
    __syncthreads();

    // ---- Stage A: radix-2, stride 512, twiddle W_1024^u ----
#pragma unroll
    for (int q = 0; q < 4; ++q) {
        int u = f + 128 * q;
        float2 a = Zb[SWZ(u)], d = Zb[SWZ(u + 512)];
        Zb[SWZ(u)]       = cadd(a, d);
        Zb[SWZ(u + 512)] = cmul(csub(a, d), su.lut[u]);
    }
    __syncthreads();

    // ---- Stage B: radix-8 on two length-512 subs, stride 64 ----
    {
        const int base = (f >> 6) * 512 + (f & 63);
        float2 v[8];
#pragma unroll
        for (int r = 0; r < 8; ++r) v[r] = Zb[SWZ(base + 64 * r)];
        dft8(v);
        twiddle8(v, su.lut[2 * (f & 63)]);
#pragma unroll
        for (int k = 0; k < 8; ++k) Zb[SWZ(base + 64 * k)] = v[k];
    }
    __syncthreads();

    // ---- Stage C: radix-8 on 16 length-64 subs, stride 8 (last lut use) ----
    {
        const int base = (f >> 3) * 64 + (f & 7);
        float2 v[8];
#pragma unroll
        for (int r = 0; r < 8; ++r) v[r] = Zb[SWZ(base + 8 * r)];
        dft8(v);
        twiddle8(v, su.lut[16 * (f & 7)]);
#pragma unroll
        for (int k = 0; k < 8; ++k) Zb[SWZ(base + 8 * k)] = v[k];
    }
    __syncthreads();

    // ---- Stage D: radix-8 on 128 length-8 subs, stride 1 (no twiddle) ----
    {
        const int base = f * 8;
        float2 v[8];
#pragma unroll
        for (int r = 0; r < 8; ++r) v[r] = Zb[SWZ(base + r)];
        dft8(v);
#pragma unroll
        for (int k = 0; k < 8; ++k) Zb[SWZ(base + k)] = v[k];
    }
    __syncthreads();

    // ---- Phases 2+3: double-buffered A, one barrier per chunk ----
    const int lane = tid & 63, wv = tid >> 6;
    const int mt = wv >> 2, nt = wv & 3;
    const int l15 = lane & 15, quad = lane >> 4;
    const int arow = mt * 16 + l15;
    const _Float16* Bbase = g_Btw + (nt * 16 + l15) * KTOT;
    floatx4 acc = {0.0f, 0.0f, 0.0f, 0.0f};

    const int bl = tid & 127, pg = tid >> 7;   // A-fill: (bin-local, pair-group of 7)

    auto fillA = [&](int h, _Float16* Abuf) {
        const int beta = h * 128 + bl;
        const int pa = posmap(beta);
        const int pb = posmap((1024 - beta) & 1023);
        float2 Xs[8];
#pragma unroll
        for (int cc = 0; cc < 4; ++cc) {
            float2 Aa = s_z[cc * ZPITCH + SWZ(pa)];
            float2 Bb = s_z[cc * ZPITCH + SWZ(pb)];
            Xs[2 * cc]     = make_float2(0.5f * (Aa.x + Bb.x), 0.5f * (Aa.y - Bb.y));
            Xs[2 * cc + 1] = make_float2(0.5f * (Aa.y + Bb.y), 0.5f * (Bb.x - Aa.x));
        }
#pragma unroll
        for (int pp = 0; pp < 7; ++pp) {
            const int p = pg * 7 + pp;
            float2 X1 = Xs[c_i1[p]], X2 = Xs[c_i2[p]];
            float rr = X1.x * X2.x + X1.y * X2.y;
            float ri = X1.y * X2.x - X1.x * X2.y;
            float m2 = rr * rr + ri * ri;
            float inv = (m2 > 1e-30f) ? rsqrtf(m2) : 0.0f;
            *(half2t*)&Abuf[p * APITCH + 2 * bl] =
                (half2t){(_Float16)(rr * inv), (_Float16)(ri * inv)};
        }
        if (h == 0 && bl == 0) {               // Nyquist -> hijacked col k=1
#pragma unroll
            for (int pp = 0; pp < 7; ++pp) {
                const int p = pg * 7 + pp;
                const int pN = posmap(512);    // = 4
                float2 Za = s_z[(c_i1[p] >> 1) * ZPITCH + SWZ(pN)];
                float2 Zc = s_z[(c_i2[p] >> 1) * ZPITCH + SWZ(pN)];
                float x1 = (c_i1[p] & 1) ? Za.y : Za.x;
                float x2 = (c_i2[p] & 1) ? Zc.y : Zc.x;
                float rr = x1 * x2;
                float inv = (rr * rr > 1e-30f) ? rsqrtf(rr * rr) : 0.0f;
                Abuf[p * APITCH + 1] = (_Float16)(rr * inv);
            }
        }
    };

    fillA(0, su.A[0]);
    __syncthreads();

    for (int h = 0; h < NCHUNK; ++h) {
        if (h + 1 < NCHUNK) fillA(h + 1, su.A[(h + 1) & 1]);

        const _Float16* Ap = su.A[h & 1] + arow * APITCH;
        const _Float16* Bp = Bbase + h * CH_K;
#pragma unroll
        for (int kt = 0; kt < NKT; ++kt) {
            half8 af = *(const half8*)(Ap + kt * 32 + quad * 8);
            half8 bf = *(const half8*)(Bp + kt * 32 + quad * 8);
            acc = __builtin_amdgcn_mfma_f32_16x16x32_f16(af, bf, acc, 0, 0, 0);
        }
        __syncthreads();
    }

    // ---- Epilogue: C/D layout col=lane&15, row=quad*4+reg ----
#pragma unroll
    for (int r = 0; r < 4; ++r) {
        int pair = mt * 16 + quad * 4 + r;
        if (pair < NPAIR)
            out[((((size_t)b * NPAIR + pair) * T_ + t) << 6) + nt * 16 + l15] = acc[r];
    }
}

extern "C" void kernel_launch(void* const* d_in, const int* in_sizes, int n_in,
                              void* d_out, int out_size, void* d_ws, size_t ws_size,
                              hipStream_t stream) {
    (void)in_sizes; (void)n_in; (void)d_ws; (void)ws_size; (void)out_size;
    hipLaunchKernelGGL(init_btw, dim3(256), dim3(256), 0, stream);
    hipLaunchKernelGGL(gcc_main, dim3(T_, B_), dim3(512), 0, stream,
                       (const float*)d_in[0], (float*)d_out);
}

// Round 5
// 341.283 us; speedup vs baseline: 1.3392x; 1.2213x over previous
//
#include <hip/hip_runtime.h>
#include <math.h>

#define B_    16
#define M_    8
#define T_    250
#define L_    1024
#define NPAIR 28

#define KTOT   1024
#define CH_K   256
#define APITCH 264      // 256 + 8 halfs pad; row stride 528 B (16B multiple)
#define NKT    8
#define NCHUNK 4
#define ZPITCH 1056     // SWZ(1023)+1 rounded

typedef _Float16 half8  __attribute__((ext_vector_type(8)));
typedef _Float16 half2t __attribute__((ext_vector_type(2)));
typedef float    floatx4 __attribute__((ext_vector_type(4)));

__device__ __align__(16) _Float16 g_Btw[64 * KTOT];

// np.triu_indices(8, k=1) — used only by the (rare) Nyquist fixup
__constant__ int c_i1[NPAIR] = {0,0,0,0,0,0,0,1,1,1,1,1,1,2,2,2,2,2,3,3,3,3,4,4,4,5,5,6};
__constant__ int c_i2[NPAIR] = {1,2,3,4,5,6,7,2,3,4,5,6,7,3,4,5,6,7,4,5,6,7,5,6,7,6,7,7};

// B[n][k]: k=0 -> DC (1/1024); k=1 -> Nyquist slot ((-1)^n/1024); k=2b -> 2cos/1024, 2b+1 -> -2sin/1024
__global__ void init_btw() {
    int idx = blockIdx.x * 256 + threadIdx.x;
    int n = idx >> 10, k = idx & 1023;
    float v;
    if (k == 0)      v = 1.0f / 1024.0f;
    else if (k == 1) v = (n & 1) ? (-1.0f / 1024.0f) : (1.0f / 1024.0f);
    else {
        int bin = k >> 1, tau = n - 32;
        int r = (tau * bin) & 1023;
        float ang = (float)r * (6.283185307179586f / 1024.0f);
        float s, c; sincosf(ang, &s, &c);
        v = ((k & 1) ? -s : c) * (2.0f / 1024.0f);
    }
    g_Btw[idx] = (_Float16)v;
}

#define SWZ(i) ((i) + ((i) >> 5))

__device__ inline float2 cmul(float2 a, float2 b) {
    return make_float2(fmaf(a.x, b.x, -a.y * b.y), fmaf(a.x, b.y, a.y * b.x));
}
__device__ inline float2 cadd(float2 a, float2 b) { return make_float2(a.x + b.x, a.y + b.y); }
__device__ inline float2 csub(float2 a, float2 b) { return make_float2(a.x - b.x, a.y - b.y); }
__device__ inline float2 cmni(float2 a) { return make_float2(a.y, -a.x); }  // a * (-i)

// DIF 8-point DFT: y_k = sum_r v_r W8^{rk}, in place
__device__ inline void dft8(float2 v[8]) {
    const float rt = 0.70710678118654752440f;
    float2 b0 = cadd(v[0], v[4]), b1 = cadd(v[1], v[5]);
    float2 b2 = cadd(v[2], v[6]), b3 = cadd(v[3], v[7]);
    float2 c0 = csub(v[0], v[4]);
    float2 t1 = csub(v[1], v[5]);
    float2 c1 = make_float2(rt * (t1.x + t1.y), rt * (t1.y - t1.x));   // *W8^1
    float2 c2 = cmni(csub(v[2], v[6]));                                 // *W8^2
    float2 t3 = csub(v[3], v[7]);
    float2 c3 = make_float2(rt * (t3.y - t3.x), -rt * (t3.x + t3.y));  // *W8^3
    float2 f0 = cadd(b0, b2), f1 = cadd(b1, b3);
    float2 g0 = csub(b0, b2), g1 = cmni(csub(b1, b3));
    v[0] = cadd(f0, f1); v[4] = csub(f0, f1);
    v[2] = cadd(g0, g1); v[6] = csub(g0, g1);
    f0 = cadd(c0, c2); f1 = cadd(c1, c3);
    g0 = csub(c0, c2); g1 = cmni(csub(c1, c3));
    v[1] = cadd(f0, f1); v[5] = csub(f0, f1);
    v[3] = cadd(g0, g1); v[7] = csub(g0, g1);
}

__device__ inline void twiddle8(float2 v[8], float2 w1) {
    float2 w = w1;
    v[1] = cmul(v[1], w);
#pragma unroll
    for (int k = 2; k < 8; ++k) { w = cmul(w, w1); v[k] = cmul(v[k], w); }
}

// DIF radices (2,8,8,8): X[k] sits at p(k)
__device__ inline int posmap(int k) {
    return ((k & 1) << 9) | (((k >> 1) & 7) << 6) | (((k >> 4) & 7) << 3) | ((k >> 7) & 7);
}

__global__ __launch_bounds__(512, 4) void gcc_main(const float* __restrict__ x,
                                                   float* __restrict__ out) {
    __shared__ float2 s_z[4 * ZPITCH];                                  // 33792 B
    // lut (4 KB) overlaps A[0]; lut's last use (stage C) precedes first A[0] write
    __shared__ __align__(16) union {
        float2   lut[512];
        _Float16 A[2][32 * APITCH];
    } su;                                                               // 33792 B

    const int tid = threadIdx.x;
    const int t = blockIdx.x, b = blockIdx.y;
    const int f = tid & 127, c = tid >> 7;
    float2* Zb = s_z + c * ZPITCH;

    // lut[m] = W_1024^m = e^{-2 pi i m / 1024}, m in [0,512)
    {
        float s, cv, ang = (float)tid * (-6.283185307179586f / 1024.0f);
        sincosf(ang, &s, &cv);
        su.lut[tid] = make_float2(cv, s);
    }

    // ---- load: pack channels (2c, 2c+1) into complex Z_c ----
    const float* xa = x + (((size_t)b * M_ + 2 * c) * T_ + t) * L_;
    const float* xb = xa + (size_t)T_ * L_;
#pragma unroll
    for (int e = 0; e < 2; ++e) {
        float4 va = *(const float4*)(xa + f * 8 + e * 4);
        float4 vb = *(const float4*)(xb + f * 8 + e * 4);
        int i = f * 8 + e * 4;
        Zb[SWZ(i + 0)] = make_float2(va.x, vb.x);
        Zb[SWZ(i + 1)] = make_float2(va.y, vb.y);
        Zb[SWZ(i + 2)] = make_float2(va.z, vb.z);
        Zb[SWZ(i + 3)] = make_float2(va.w, vb.w);
    }
    __syncthreads();

    // ---- Stage A: radix-2, stride 512, twiddle W_1024^u ----
#pragma unroll
    for (int q = 0; q < 4; ++q) {
        int u = f + 128 * q;
        float2 a = Zb[SWZ(u)], d = Zb[SWZ(u + 512)];
        Zb[SWZ(u)]       = cadd(a, d);
        Zb[SWZ(u + 512)] = cmul(csub(a, d), su.lut[u]);
    }
    __syncthreads();

    // ---- Stage B: radix-8 on two length-512 subs, stride 64 ----
    {
        const int base = (f >> 6) * 512 + (f & 63);
        float2 v[8];
#pragma unroll
        for (int r = 0; r < 8; ++r) v[r] = Zb[SWZ(base + 64 * r)];
        dft8(v);
        twiddle8(v, su.lut[2 * (f & 63)]);
#pragma unroll
        for (int k = 0; k < 8; ++k) Zb[SWZ(base + 64 * k)] = v[k];
    }
    __syncthreads();

    // ---- Stage C: radix-8 on 16 length-64 subs, stride 8 (last lut use) ----
    {
        const int base = (f >> 3) * 64 + (f & 7);
        float2 v[8];
#pragma unroll
        for (int r = 0; r < 8; ++r) v[r] = Zb[SWZ(base + 8 * r)];
        dft8(v);
        twiddle8(v, su.lut[16 * (f & 7)]);
#pragma unroll
        for (int k = 0; k < 8; ++k) Zb[SWZ(base + 8 * k)] = v[k];
    }
    __syncthreads();

    // ---- Stage D: radix-8 on 128 length-8 subs, stride 1 (no twiddle) ----
    {
        const int base = f * 8;
        float2 v[8];
#pragma unroll
        for (int r = 0; r < 8; ++r) v[r] = Zb[SWZ(base + r)];
        dft8(v);
#pragma unroll
        for (int k = 0; k < 8; ++k) Zb[SWZ(base + k)] = v[k];
    }
    __syncthreads();

    // ---- Phases 2+3: double-buffered A, one barrier per chunk ----
    const int lane = tid & 63, wv = tid >> 6;
    const int mt = wv >> 2, nt = wv & 3;
    const int l15 = lane & 15, quad = lane >> 4;
    const int arow = mt * 16 + l15;
    const _Float16* Bbase = g_Btw + (nt * 16 + l15) * KTOT;
    floatx4 acc = {0.0f, 0.0f, 0.0f, 0.0f};

    const int bl = tid & 127, pg = tid >> 7;   // A-fill: (bin-local, pair-group of 7)

    // COMPILE-TIME pair indices only — dynamic indexing of Xs forces it to
    // scratch (round 3/4: 200-460 MB of HBM scratch traffic).
#define PAIRA(p_, a_, b_)                                                     \
    {                                                                         \
        float2 X1 = Xs[a_], X2 = Xs[b_];                                      \
        float rr = X1.x * X2.x + X1.y * X2.y;                                 \
        float ri = X1.y * X2.x - X1.x * X2.y;                                 \
        float m2 = rr * rr + ri * ri;                                         \
        float inv = (m2 > 1e-30f) ? rsqrtf(m2) : 0.0f;                        \
        *(half2t*)&Abuf[(p_) * APITCH + 2 * bl] =                             \
            (half2t){(_Float16)(rr * inv), (_Float16)(ri * inv)};             \
    }

    auto fillA = [&](int h, _Float16* Abuf) {
        const int beta = h * 128 + bl;
        const int pa = posmap(beta);
        const int pb = posmap((1024 - beta) & 1023);
        float2 Xs[8];
#pragma unroll
        for (int cc = 0; cc < 4; ++cc) {
            float2 Aa = s_z[cc * ZPITCH + SWZ(pa)];
            float2 Bb = s_z[cc * ZPITCH + SWZ(pb)];
            Xs[2 * cc]     = make_float2(0.5f * (Aa.x + Bb.x), 0.5f * (Aa.y - Bb.y));
            Xs[2 * cc + 1] = make_float2(0.5f * (Aa.y + Bb.y), 0.5f * (Bb.x - Aa.x));
        }
        // pg is wave-uniform (tid>>7): 4-way uniform branch, literal indices
        if (pg == 0) {
            PAIRA(0, 0, 1) PAIRA(1, 0, 2) PAIRA(2, 0, 3) PAIRA(3, 0, 4)
            PAIRA(4, 0, 5) PAIRA(5, 0, 6) PAIRA(6, 0, 7)
        } else if (pg == 1) {
            PAIRA(7, 1, 2) PAIRA(8, 1, 3) PAIRA(9, 1, 4) PAIRA(10, 1, 5)
            PAIRA(11, 1, 6) PAIRA(12, 1, 7) PAIRA(13, 2, 3)
        } else if (pg == 2) {
            PAIRA(14, 2, 4) PAIRA(15, 2, 5) PAIRA(16, 2, 6) PAIRA(17, 2, 7)
            PAIRA(18, 3, 4) PAIRA(19, 3, 5) PAIRA(20, 3, 6)
        } else {
            PAIRA(21, 3, 7) PAIRA(22, 4, 5) PAIRA(23, 4, 6) PAIRA(24, 4, 7)
            PAIRA(25, 5, 6) PAIRA(26, 5, 7) PAIRA(27, 6, 7)
        }
        if (h == 0 && bl == 0) {               // Nyquist -> hijacked col k=1 (LDS reads only)
#pragma unroll
            for (int pp = 0; pp < 7; ++pp) {
                const int p = pg * 7 + pp;
                const int pN = posmap(512);    // = 4
                float2 Za = s_z[(c_i1[p] >> 1) * ZPITCH + SWZ(pN)];
                float2 Zc = s_z[(c_i2[p] >> 1) * ZPITCH + SWZ(pN)];
                float x1 = (c_i1[p] & 1) ? Za.y : Za.x;
                float x2 = (c_i2[p] & 1) ? Zc.y : Zc.x;
                float rr = x1 * x2;
                float inv = (rr * rr > 1e-30f) ? rsqrtf(rr * rr) : 0.0f;
                Abuf[p * APITCH + 1] = (_Float16)(rr * inv);
            }
        }
    };

    fillA(0, su.A[0]);
    __syncthreads();

    for (int h = 0; h < NCHUNK; ++h) {
        if (h + 1 < NCHUNK) fillA(h + 1, su.A[(h + 1) & 1]);

        const _Float16* Ap = su.A[h & 1] + arow * APITCH;
        const _Float16* Bp = Bbase + h * CH_K;
#pragma unroll
        for (int kt = 0; kt < NKT; ++kt) {
            half8 af = *(const half8*)(Ap + kt * 32 + quad * 8);
            half8 bf = *(const half8*)(Bp + kt * 32 + quad * 8);
            acc = __builtin_amdgcn_mfma_f32_16x16x32_f16(af, bf, acc, 0, 0, 0);
        }
        __syncthreads();
    }

    // ---- Epilogue: C/D layout col=lane&15, row=quad*4+reg ----
#pragma unroll
    for (int r = 0; r < 4; ++r) {
        int pair = mt * 16 + quad * 4 + r;
        if (pair < NPAIR)
            out[((((size_t)b * NPAIR + pair) * T_ + t) << 6) + nt * 16 + l15] = acc[r];
    }
}

extern "C" void kernel_launch(void* const* d_in, const int* in_sizes, int n_in,
                              void* d_out, int out_size, void* d_ws, size_t ws_size,
                              hipStream_t stream) {
    (void)in_sizes; (void)n_in; (void)d_ws; (void)ws_size; (void)out_size;
    hipLaunchKernelGGL(init_btw, dim3(256), dim3(256), 0, stream);
    hipLaunchKernelGGL(gcc_main, dim3(T_, B_), dim3(512), 0, stream,
                       (const float*)d_in[0], (float*)d_out);
}

// Round 6
// 294.718 us; speedup vs baseline: 1.5507x; 1.1580x over previous
//
#include <hip/hip_runtime.h>
#include <math.h>

#define B_    16
#define M_    8
#define T_    250
#define L_    1024
#define NPAIR 28

#define KTOT   1024
#define CH_K   256
#define APITCH 264      // 256 + 8 halfs pad; row stride 528 B (16B multiple)
#define NKT    8
#define NCHUNK 4
#define ZPITCH 1056     // SWZ(1023)+1 rounded

typedef _Float16 half8  __attribute__((ext_vector_type(8)));
typedef _Float16 half2t __attribute__((ext_vector_type(2)));
typedef float    floatx4 __attribute__((ext_vector_type(4)));

__device__ __align__(16) _Float16 g_Btw[64 * KTOT];

// np.triu_indices(8, k=1) — used only by the (rare) Nyquist fixup
__constant__ int c_i1[NPAIR] = {0,0,0,0,0,0,0,1,1,1,1,1,1,2,2,2,2,2,3,3,3,3,4,4,4,5,5,6};
__constant__ int c_i2[NPAIR] = {1,2,3,4,5,6,7,2,3,4,5,6,7,3,4,5,6,7,4,5,6,7,5,6,7,6,7,7};

// B[n][k]: k=0 -> DC (1/1024); k=1 -> Nyquist slot ((-1)^n/1024); k=2b -> 2cos/1024, 2b+1 -> -2sin/1024
__global__ void init_btw() {
    int idx = blockIdx.x * 256 + threadIdx.x;
    int n = idx >> 10, k = idx & 1023;
    float v;
    if (k == 0)      v = 1.0f / 1024.0f;
    else if (k == 1) v = (n & 1) ? (-1.0f / 1024.0f) : (1.0f / 1024.0f);
    else {
        int bin = k >> 1, tau = n - 32;
        int r = (tau * bin) & 1023;
        float ang = (float)r * (6.283185307179586f / 1024.0f);
        float s, c; sincosf(ang, &s, &c);
        v = ((k & 1) ? -s : c) * (2.0f / 1024.0f);
    }
    g_Btw[idx] = (_Float16)v;
}

#define SWZ(i) ((i) + ((i) >> 5))

__device__ inline float2 cmul(float2 a, float2 b) {
    return make_float2(fmaf(a.x, b.x, -a.y * b.y), fmaf(a.x, b.y, a.y * b.x));
}
__device__ inline float2 cadd(float2 a, float2 b) { return make_float2(a.x + b.x, a.y + b.y); }
__device__ inline float2 csub(float2 a, float2 b) { return make_float2(a.x - b.x, a.y - b.y); }
__device__ inline float2 cmni(float2 a) { return make_float2(a.y, -a.x); }  // a * (-i)

// DIF 8-point DFT: y_k = sum_r v_r W8^{rk}, in place
__device__ inline void dft8(float2 v[8]) {
    const float rt = 0.70710678118654752440f;
    float2 b0 = cadd(v[0], v[4]), b1 = cadd(v[1], v[5]);
    float2 b2 = cadd(v[2], v[6]), b3 = cadd(v[3], v[7]);
    float2 c0 = csub(v[0], v[4]);
    float2 t1 = csub(v[1], v[5]);
    float2 c1 = make_float2(rt * (t1.x + t1.y), rt * (t1.y - t1.x));   // *W8^1
    float2 c2 = cmni(csub(v[2], v[6]));                                 // *W8^2
    float2 t3 = csub(v[3], v[7]);
    float2 c3 = make_float2(rt * (t3.y - t3.x), -rt * (t3.x + t3.y));  // *W8^3
    float2 f0 = cadd(b0, b2), f1 = cadd(b1, b3);
    float2 g0 = csub(b0, b2), g1 = cmni(csub(b1, b3));
    v[0] = cadd(f0, f1); v[4] = csub(f0, f1);
    v[2] = cadd(g0, g1); v[6] = csub(g0, g1);
    f0 = cadd(c0, c2); f1 = cadd(c1, c3);
    g0 = csub(c0, c2); g1 = cmni(csub(c1, c3));
    v[1] = cadd(f0, f1); v[5] = csub(f0, f1);
    v[3] = cadd(g0, g1); v[7] = csub(g0, g1);
}

__device__ inline void twiddle8(float2 v[8], float2 w1) {
    float2 w = w1;
    v[1] = cmul(v[1], w);
#pragma unroll
    for (int k = 2; k < 8; ++k) { w = cmul(w, w1); v[k] = cmul(v[k], w); }
}

// DIF radices (2,8,8,8): X[k] sits at p(k)
__device__ inline int posmap(int k) {
    return ((k & 1) << 9) | (((k >> 1) & 7) << 6) | (((k >> 4) & 7) << 3) | ((k >> 7) & 7);
}

__global__ __launch_bounds__(512, 4) void gcc_main(const float* __restrict__ x,
                                                   float* __restrict__ out) {
    __shared__ float2 s_z[4 * ZPITCH];                                  // 33792 B
    // Single A buffer (16.9 KB) unioned with lut -> total LDS 50688 B -> 3 blocks/CU.
    // (Round 4/5's A double-buffer cost 16.9 KB and capped us at 2 blocks/CU;
    //  at these barrier counts the extra co-resident block is worth more.)
    __shared__ __align__(16) union {
        float2   lut[512];
        _Float16 A[32 * APITCH];
    } su;                                                               // 16896 B

    const int tid = threadIdx.x;
    const int t = blockIdx.x, b = blockIdx.y;
    const int f = tid & 127, c = tid >> 7;
    float2* Zb = s_z + c * ZPITCH;

    // lut[m] = W_1024^m = e^{-2 pi i m / 1024}, m in [0,512)
    {
        float s, cv, ang = (float)tid * (-6.283185307179586f / 1024.0f);
        sincosf(ang, &s, &cv);
        su.lut[tid] = make_float2(cv, s);
    }

    // ---- load: pack channels (2c, 2c+1) into complex Z_c ----
    const float* xa = x + (((size_t)b * M_ + 2 * c) * T_ + t) * L_;
    const float* xb = xa + (size_t)T_ * L_;
#pragma unroll
    for (int e = 0; e < 2; ++e) {
        float4 va = *(const float4*)(xa + f * 8 + e * 4);
        float4 vb = *(const float4*)(xb + f * 8 + e * 4);
        int i = f * 8 + e * 4;
        Zb[SWZ(i + 0)] = make_float2(va.x, vb.x);
        Zb[SWZ(i + 1)] = make_float2(va.y, vb.y);
        Zb[SWZ(i + 2)] = make_float2(va.z, vb.z);
        Zb[SWZ(i + 3)] = make_float2(va.w, vb.w);
    }
    __syncthreads();

    // ---- Stage A: radix-2, stride 512, twiddle W_1024^u ----
#pragma unroll
    for (int q = 0; q < 4; ++q) {
        int u = f + 128 * q;
        float2 a = Zb[SWZ(u)], d = Zb[SWZ(u + 512)];
        Zb[SWZ(u)]       = cadd(a, d);
        Zb[SWZ(u + 512)] = cmul(csub(a, d), su.lut[u]);
    }
    __syncthreads();

    // ---- Stage B: radix-8 on two length-512 subs, stride 64 ----
    {
        const int base = (f >> 6) * 512 + (f & 63);
        float2 v[8];
#pragma unroll
        for (int r = 0; r < 8; ++r) v[r] = Zb[SWZ(base + 64 * r)];
        dft8(v);
        twiddle8(v, su.lut[2 * (f & 63)]);
#pragma unroll
        for (int k = 0; k < 8; ++k) Zb[SWZ(base + 64 * k)] = v[k];
    }
    __syncthreads();

    // ---- Stage C: radix-8 on 16 length-64 subs, stride 8 (last lut use) ----
    {
        const int base = (f >> 3) * 64 + (f & 7);
        float2 v[8];
#pragma unroll
        for (int r = 0; r < 8; ++r) v[r] = Zb[SWZ(base + 8 * r)];
        dft8(v);
        twiddle8(v, su.lut[16 * (f & 7)]);
#pragma unroll
        for (int k = 0; k < 8; ++k) Zb[SWZ(base + 8 * k)] = v[k];
    }
    __syncthreads();

    // ---- Stage D: radix-8 on 128 length-8 subs, stride 1 (no twiddle) ----
    {
        const int base = f * 8;
        float2 v[8];
#pragma unroll
        for (int r = 0; r < 8; ++r) v[r] = Zb[SWZ(base + r)];
        dft8(v);
#pragma unroll
        for (int k = 0; k < 8; ++k) Zb[SWZ(base + k)] = v[k];
    }
    __syncthreads();

    // ---- Phases 2+3: single A buffer, fill -> barrier -> MFMA -> barrier ----
    const int lane = tid & 63, wv = tid >> 6;
    const int mt = wv >> 2, nt = wv & 3;
    const int l15 = lane & 15, quad = lane >> 4;
    const int arow = mt * 16 + l15;
    const _Float16* Bbase = g_Btw + (nt * 16 + l15) * KTOT;
    floatx4 acc = {0.0f, 0.0f, 0.0f, 0.0f};

    const int bl = tid & 127, pg = tid >> 7;   // A-fill: (bin-local, pair-group of 7)

    // COMPILE-TIME pair indices only — dynamic indexing of Xs forces it to
    // scratch (round 3/4: 200-460 MB of HBM scratch traffic).
#define PAIRA(p_, a_, b_)                                                     \
    {                                                                         \
        float2 X1 = Xs[a_], X2 = Xs[b_];                                      \
        float rr = X1.x * X2.x + X1.y * X2.y;                                 \
        float ri = X1.y * X2.x - X1.x * X2.y;                                 \
        float m2 = rr * rr + ri * ri;                                         \
        float inv = (m2 > 1e-30f) ? rsqrtf(m2) : 0.0f;                        \
        *(half2t*)&su.A[(p_) * APITCH + 2 * bl] =                             \
            (half2t){(_Float16)(rr * inv), (_Float16)(ri * inv)};             \
    }

    auto fillA = [&](int h) {
        const int beta = h * 128 + bl;
        const int pa = posmap(beta);
        const int pb = posmap((1024 - beta) & 1023);
        float2 Xs[8];
#pragma unroll
        for (int cc = 0; cc < 4; ++cc) {
            float2 Aa = s_z[cc * ZPITCH + SWZ(pa)];
            float2 Bb = s_z[cc * ZPITCH + SWZ(pb)];
            Xs[2 * cc]     = make_float2(0.5f * (Aa.x + Bb.x), 0.5f * (Aa.y - Bb.y));
            Xs[2 * cc + 1] = make_float2(0.5f * (Aa.y + Bb.y), 0.5f * (Bb.x - Aa.x));
        }
        // pg is wave-uniform (tid>>7): 4-way uniform branch, literal indices
        if (pg == 0) {
            PAIRA(0, 0, 1) PAIRA(1, 0, 2) PAIRA(2, 0, 3) PAIRA(3, 0, 4)
            PAIRA(4, 0, 5) PAIRA(5, 0, 6) PAIRA(6, 0, 7)
        } else if (pg == 1) {
            PAIRA(7, 1, 2) PAIRA(8, 1, 3) PAIRA(9, 1, 4) PAIRA(10, 1, 5)
            PAIRA(11, 1, 6) PAIRA(12, 1, 7) PAIRA(13, 2, 3)
        } else if (pg == 2) {
            PAIRA(14, 2, 4) PAIRA(15, 2, 5) PAIRA(16, 2, 6) PAIRA(17, 2, 7)
            PAIRA(18, 3, 4) PAIRA(19, 3, 5) PAIRA(20, 3, 6)
        } else {
            PAIRA(21, 3, 7) PAIRA(22, 4, 5) PAIRA(23, 4, 6) PAIRA(24, 4, 7)
            PAIRA(25, 5, 6) PAIRA(26, 5, 7) PAIRA(27, 6, 7)
        }
        if (h == 0 && bl == 0) {               // Nyquist -> hijacked col k=1 (LDS reads only)
#pragma unroll
            for (int pp = 0; pp < 7; ++pp) {
                const int p = pg * 7 + pp;
                const int pN = posmap(512);    // = 4
                float2 Za = s_z[(c_i1[p] >> 1) * ZPITCH + SWZ(pN)];
                float2 Zc = s_z[(c_i2[p] >> 1) * ZPITCH + SWZ(pN)];
                float x1 = (c_i1[p] & 1) ? Za.y : Za.x;
                float x2 = (c_i2[p] & 1) ? Zc.y : Zc.x;
                float rr = x1 * x2;
                float inv = (rr * rr > 1e-30f) ? rsqrtf(rr * rr) : 0.0f;
                su.A[p * APITCH + 1] = (_Float16)(rr * inv);
            }
        }
    };

    for (int h = 0; h < NCHUNK; ++h) {
        fillA(h);
        __syncthreads();

        const _Float16* Ap = su.A + arow * APITCH;
        const _Float16* Bp = Bbase + h * CH_K;
#pragma unroll
        for (int kt = 0; kt < NKT; ++kt) {
            half8 af = *(const half8*)(Ap + kt * 32 + quad * 8);
            half8 bf = *(const half8*)(Bp + kt * 32 + quad * 8);
            acc = __builtin_amdgcn_mfma_f32_16x16x32_f16(af, bf, acc, 0, 0, 0);
        }
        __syncthreads();
    }

    // ---- Epilogue: C/D layout col=lane&15, row=quad*4+reg ----
#pragma unroll
    for (int r = 0; r < 4; ++r) {
        int pair = mt * 16 + quad * 4 + r;
        if (pair < NPAIR)
            out[((((size_t)b * NPAIR + pair) * T_ + t) << 6) + nt * 16 + l15] = acc[r];
    }
}

extern "C" void kernel_launch(void* const* d_in, const int* in_sizes, int n_in,
                              void* d_out, int out_size, void* d_ws, size_t ws_size,
                              hipStream_t stream) {
    (void)in_sizes; (void)n_in; (void)d_ws; (void)ws_size; (void)out_size;
    hipLaunchKernelGGL(init_btw, dim3(256), dim3(256), 0, stream);
    hipLaunchKernelGGL(gcc_main, dim3(T_, B_), dim3(512), 0, stream,
                       (const float*)d_in[0], (float*)d_out);
}